// Round 12
// baseline (144.978 us; speedup 1.0000x reference)
//
#include <hip/hip_runtime.h>
#include <math.h>

#define BB 4
#define LL 4096
#define DD 256
#define NROWS (BB*LL)      // 16384
#define CHUNK 32
#define NC (LL/CHUNK)      // 128
#define NB 8192            // counting-sort bins

typedef __bf16 bf16x8 __attribute__((ext_vector_type(8)));
typedef __bf16 bf16x4 __attribute__((ext_vector_type(4)));
typedef float floatx4 __attribute__((ext_vector_type(4)));

// ---------------- K1: u = {Wq^T w, Wk^T w} + split Wv -> Wh+Wl (no atomics, no memset) ----------------
__global__ void __launch_bounds__(256) k_prep(const float* __restrict__ Wq,
        const float* __restrict__ Wk, const float* __restrict__ Wv,
        const float* __restrict__ w, float* __restrict__ u,
        __bf16* __restrict__ Wh, __bf16* __restrict__ Wl) {
    __shared__ float pq[256*17];
    __shared__ float pk[256*17];
    __shared__ float rq[16*17], rk[16*17];
    int e = threadIdx.x;
    int d0 = blockIdx.x * 16;
    float we = w[e];
    #pragma unroll
    for (int j4 = 0; j4 < 4; ++j4) {
        float4 q4 = *(const float4*)(Wq + (size_t)e*DD + d0 + j4*4);
        float4 k4 = *(const float4*)(Wk + (size_t)e*DD + d0 + j4*4);
        float4 v4 = *(const float4*)(Wv + (size_t)e*DD + d0 + j4*4);
        float qa[4] = {q4.x, q4.y, q4.z, q4.w};
        float ka[4] = {k4.x, k4.y, k4.z, k4.w};
        float va[4] = {v4.x, v4.y, v4.z, v4.w};
        #pragma unroll
        for (int j = 0; j < 4; ++j) {
            pq[e*17 + j4*4 + j] = qa[j] * we;
            pk[e*17 + j4*4 + j] = ka[j] * we;
            __bf16 h = (__bf16)va[j];
            Wh[(size_t)e*DD + d0 + j4*4 + j] = h;
            Wl[(size_t)e*DD + d0 + j4*4 + j] = (__bf16)(va[j] - (float)h);
        }
    }
    __syncthreads();
    int d = e & 15, g = e >> 4;
    float sq = 0.f, sk = 0.f;
    #pragma unroll
    for (int i = 0; i < 16; ++i) {
        sq += pq[(g*16 + i)*17 + d];
        sk += pk[(g*16 + i)*17 + d];
    }
    rq[g*17 + d] = sq;
    rk[g*17 + d] = sk;
    __syncthreads();
    if (e < 16) {
        float s1 = 0.f, s2 = 0.f;
        #pragma unroll
        for (int gg = 0; gg < 16; ++gg) { s1 += rq[gg*17 + e]; s2 += rk[gg*17 + e]; }
        u[d0 + e] = s1;
        u[DD + d0 + e] = s2;
    }
}

// ---------------- K2: V = x @ Wv^T via split-bf16 MFMA (r9 version: LDS A-staging) ----------------
__global__ void __launch_bounds__(256) k_gemm_mfma(
        const float* __restrict__ x,
        const __bf16* __restrict__ Wh, const __bf16* __restrict__ Wl,
        const float* __restrict__ u, const float* __restrict__ bmlp,
        float* __restrict__ V, float* __restrict__ a, float* __restrict__ c) {
    __shared__ __bf16 Ah[32*40];    // 2.5 KB
    __shared__ __bf16 Al[32*40];
    __shared__ float4 ul[128];      // uq (64 float4) + uk (64 float4)
    __shared__ float pros[512];
    const int tid = threadIdx.x;
    const int wave = tid >> 6, lane = tid & 63;
    const int rowBase = blockIdx.x * 32;
    const int quad = lane >> 4, l16 = lane & 15;
    const int srow = tid >> 3, skq = (tid & 7) * 4;   // staging: 8 thr/row

    if (tid < 128) ul[tid] = ((const float4*)u)[tid];

    floatx4 acc[2][4];
    #pragma unroll
    for (int rt = 0; rt < 2; ++rt)
        #pragma unroll
        for (int ct = 0; ct < 4; ++ct)
            acc[rt][ct] = (floatx4){0.f, 0.f, 0.f, 0.f};
    float aq = 0.f, ak = 0.f;

    for (int k0 = 0; k0 < DD; k0 += 32) {
        __syncthreads();
        float4 xv = *(const float4*)(x + (size_t)(rowBase + srow)*DD + k0 + skq);
        __bf16 h0 = (__bf16)xv.x, h1 = (__bf16)xv.y, h2 = (__bf16)xv.z, h3 = (__bf16)xv.w;
        bf16x4 hv = {h0, h1, h2, h3};
        bf16x4 lv = {(__bf16)(xv.x - (float)h0), (__bf16)(xv.y - (float)h1),
                     (__bf16)(xv.z - (float)h2), (__bf16)(xv.w - (float)h3)};
        *(bf16x4*)&Ah[srow*40 + skq] = hv;
        *(bf16x4*)&Al[srow*40 + skq] = lv;
        float4 q4 = ul[(k0 >> 2) + (tid & 7)];
        float4 k4 = ul[64 + (k0 >> 2) + (tid & 7)];
        aq = fmaf(xv.x, q4.x, fmaf(xv.y, q4.y, fmaf(xv.z, q4.z, fmaf(xv.w, q4.w, aq))));
        ak = fmaf(xv.x, k4.x, fmaf(xv.y, k4.y, fmaf(xv.z, k4.z, fmaf(xv.w, k4.w, ak))));
        __syncthreads();
        bf16x8 ah[2], al[2];
        #pragma unroll
        for (int rt = 0; rt < 2; ++rt) {
            int m = rt*16 + l16;
            ah[rt] = *(bf16x8*)&Ah[m*40 + quad*8];
            al[rt] = *(bf16x8*)&Al[m*40 + quad*8];
        }
        #pragma unroll
        for (int ct = 0; ct < 4; ++ct) {
            int n = wave*64 + ct*16 + l16;
            bf16x8 bh = *(const bf16x8*)(Wh + (size_t)n*DD + k0 + quad*8);
            bf16x8 bl = *(const bf16x8*)(Wl + (size_t)n*DD + k0 + quad*8);
            #pragma unroll
            for (int rt = 0; rt < 2; ++rt) {
                acc[rt][ct] = __builtin_amdgcn_mfma_f32_16x16x32_bf16(ah[rt], bh, acc[rt][ct], 0, 0, 0);
                acc[rt][ct] = __builtin_amdgcn_mfma_f32_16x16x32_bf16(ah[rt], bl, acc[rt][ct], 0, 0, 0);
                acc[rt][ct] = __builtin_amdgcn_mfma_f32_16x16x32_bf16(al[rt], bh, acc[rt][ct], 0, 0, 0);
            }
        }
    }
    #pragma unroll
    for (int rt = 0; rt < 2; ++rt)
        #pragma unroll
        for (int ct = 0; ct < 4; ++ct)
            #pragma unroll
            for (int i = 0; i < 4; ++i) {
                int row = rowBase + rt*16 + quad*4 + i;
                int col = wave*64 + ct*16 + l16;
                V[(size_t)row*DD + col] = acc[rt][ct][i];
            }
    __syncthreads();
    pros[tid] = aq;
    pros[256 + tid] = ak;
    __syncthreads();
    if (tid < 32) {
        float sa = 0.f, sc = 0.f;
        #pragma unroll
        for (int j = 0; j < 8; ++j) {
            sa += pros[tid*8 + j];
            sc += pros[256 + tid*8 + j];
        }
        a[rowBase + tid] = sa + bmlp[0];
        c[rowBase + tid] = sc;
    }
}

// ---------------- K3: counting sort + BIN-LEVEL SE (no rank-order SE scan) ----------------
// SE is only consumed at bin boundaries k=binstart[ib], so SE[k] = prefix of
// per-bin e-sums. Accumulate ehist with LDS float atomics during histogram,
// fold into the existing bin scan. Removes the 4096-elem rank scan (+esl).
__global__ void __launch_bounds__(1024) k_sortish(const float* __restrict__ c,
        int* __restrict__ binstart_g,       // [BB][NB+2]
        float* __restrict__ SEb,            // [BB][NB+2] exclusive bin e-prefix
        int* __restrict__ perm,
        float* __restrict__ c_sorted, float* __restrict__ e_sorted,
        float* __restrict__ hdr) {
    __shared__ int   hist[NB];     // 32 KB
    __shared__ float ehist[NB];    // 32 KB
    __shared__ float scrf[64];     // floats [0..32), ints at [32..64)
    int b = blockIdx.x, tid = threadIdx.x;
    int wave = tid >> 6, lane = tid & 63;
    int* scri = (int*)scrf;

    // phase 1: load c, min/max
    float4 cv = ((const float4*)(c + (size_t)b*LL))[tid];
    float cw[4] = {cv.x, cv.y, cv.z, cv.w};
    float mn = fminf(fminf(cw[0],cw[1]), fminf(cw[2],cw[3]));
    float mx = fmaxf(fmaxf(cw[0],cw[1]), fmaxf(cw[2],cw[3]));
    #pragma unroll
    for (int off = 32; off > 0; off >>= 1) {
        mn = fminf(mn, __shfl_down(mn, off));
        mx = fmaxf(mx, __shfl_down(mx, off));
    }
    if (lane == 0) { scrf[wave] = mn; scrf[32 + wave] = mx; }
    __syncthreads();
    if (wave == 0) {
        float m = (lane < 16) ? scrf[lane]      :  3.4e38f;
        float M = (lane < 16) ? scrf[32 + lane] : -3.4e38f;
        #pragma unroll
        for (int off = 32; off > 0; off >>= 1) {
            m = fminf(m, __shfl_down(m, off));
            M = fmaxf(M, __shfl_down(M, off));
        }
        if (lane == 0) { scrf[0] = m; scrf[1] = M; }
    }
    __syncthreads();
    float cmin = scrf[0], cmax = scrf[1];
    float scale = (float)NB / fmaxf(cmax - cmin, 1e-20f);
    float ev[4];
    #pragma unroll
    for (int u = 0; u < 4; ++u) ev[u] = expf(cmin - cw[u]);   // <= 1
    __syncthreads();

    // phase 2: zero hist + ehist
    ((int4*)hist)[tid]  = make_int4(0,0,0,0);
    ((int4*)hist)[tid + 1024] = make_int4(0,0,0,0);
    ((float4*)ehist)[tid] = make_float4(0.f,0.f,0.f,0.f);
    ((float4*)ehist)[tid + 1024] = make_float4(0.f,0.f,0.f,0.f);
    __syncthreads();

    // phase 3: histogram (count + e-sum)
    int bins[4];
    #pragma unroll
    for (int u = 0; u < 4; ++u) {
        int bi = (int)((cw[u] - cmin) * scale);
        bi = bi < 0 ? 0 : (bi > NB-1 ? NB-1 : bi);
        bins[u] = bi;
        atomicAdd(&hist[bi], 1);
        atomicAdd(&ehist[bi], ev[u]);
    }
    __syncthreads();

    // phase 4: combined exclusive scan (int count + float e-sum), 8 bins/thread
    int loc[8]; int base = 0;
    float eloc[8]; float ebase = 0.f;
    #pragma unroll
    for (int j = 0; j < 8; ++j) {
        loc[j] = base;   base  += hist[tid*8 + j];
        eloc[j] = ebase; ebase += ehist[tid*8 + j];
    }
    int incl = base; float eincl = ebase;
    #pragma unroll
    for (int off = 1; off < 64; off <<= 1) {
        int t = __shfl_up(incl, off);
        float ft = __shfl_up(eincl, off);
        if (lane >= off) { incl += t; eincl += ft; }
    }
    if (lane == 63) { scri[32 + wave] = incl; scrf[wave] = eincl; }
    __syncthreads();
    if (wave == 0) {
        int v = (lane < 16) ? scri[32 + lane] : 0;
        float fv = (lane < 16) ? scrf[lane] : 0.f;
        int s = v; float fs = fv;
        #pragma unroll
        for (int off = 1; off < 16; off <<= 1) {
            int t = __shfl_up(s, off);
            float ft = __shfl_up(fs, off);
            if (lane >= off) { s += t; fs += ft; }
        }
        if (lane < 16) { scri[32 + lane] = s - v; scrf[lane] = fs - fv; }
    }
    __syncthreads();
    int thread_excl = (incl - base) + scri[32 + wave];
    float ethread_excl = (eincl - ebase) + scrf[wave];
    #pragma unroll
    for (int j = 0; j < 8; ++j) {
        int bs = thread_excl + loc[j];
        binstart_g[(size_t)b*(NB+2) + tid*8 + j] = bs;
        SEb[(size_t)b*(NB+2) + tid*8 + j] = ethread_excl + eloc[j];
        hist[tid*8 + j] = bs;                // LDS cursor copy for scatter
    }
    if (tid == 1023) {
        binstart_g[(size_t)b*(NB+2) + NB]     = LL;
        binstart_g[(size_t)b*(NB+2) + NB + 1] = LL;
        SEb[(size_t)b*(NB+2) + NB] = ethread_excl + ebase;   // total e
        hdr[b*2 + 0] = cmin;
        hdr[b*2 + 1] = scale;
    }
    __syncthreads();

    // phase 5: scatter
    #pragma unroll
    for (int u = 0; u < 4; ++u) {
        int i = tid*4 + u;
        int r = atomicAdd(&hist[bins[u]], 1);
        perm[(size_t)b*LL + r] = i;
        c_sorted[(size_t)b*LL + r] = cw[u];
        e_sorted[(size_t)b*LL + r] = ev[u];
    }
}

// ---------------- K4: chunked exclusive prefix over V in rank order ----------------
__global__ void k_scan(const float* __restrict__ V, const int* __restrict__ perm,
        const float* __restrict__ e_sorted,
        float* __restrict__ Pl, float* __restrict__ Pel,
        float* __restrict__ Tp, float* __restrict__ Te) {
    int b = blockIdx.y, q = blockIdx.x;
    int d = threadIdx.x;
    __shared__ int pj[CHUNK];
    __shared__ float pe[CHUNK];
    if (d < CHUNK) {
        pj[d] = perm[(size_t)b*LL + q*CHUNK + d];
        pe[d] = e_sorted[(size_t)b*LL + q*CHUNK + d];
    }
    __syncthreads();
    float vr[CHUNK];
    #pragma unroll
    for (int r = 0; r < CHUNK; ++r)
        vr[r] = V[((size_t)b*LL + pj[r]) * DD + d];
    float acc = 0.f, acce = 0.f;
    size_t kb = (size_t)b*LL + (size_t)q*CHUNK;
    #pragma unroll
    for (int r = 0; r < CHUNK; ++r) {
        size_t o = (kb + r) * DD + d;
        Pl[o]  = acc;
        Pel[o] = acce;
        acc += vr[r];
        acce = fmaf(pe[r], vr[r], acce);
    }
    size_t to = ((size_t)b*NC + q) * DD + d;
    Tp[to] = acc;
    Te[to] = acce;
}

// ---------------- K5: chunk bases, parallel over (q, b) ----------------
__global__ void k_base(const float* __restrict__ Tp, const float* __restrict__ Te,
        float* __restrict__ baseP, float* __restrict__ basePe) {
    int q = blockIdx.x, b = blockIdx.y, d = threadIdx.x;
    float acc = 0.f, acce = 0.f;
    #pragma unroll 8
    for (int i = 0; i < q; ++i) {
        size_t ti = ((size_t)b*NC + i) * DD + d;
        acc += Tp[ti]; acce += Te[ti];
    }
    size_t o = ((size_t)b*(NC+1) + q) * DD + d;
    baseP[o] = acc; basePe[o] = acce;
}

// ---------------- K6: per-row output, O(1) bin lookup + exact boundary fix ----------------
__global__ void k_out(const float* __restrict__ a, const float* __restrict__ hdr,
                      const int* __restrict__ binstart, const float* __restrict__ SEb,
                      const float* __restrict__ c_sorted, const float* __restrict__ e_sorted,
                      const int* __restrict__ perm, const float* __restrict__ V,
                      const float* __restrict__ Pl, const float* __restrict__ Pel,
                      const float* __restrict__ baseP, const float* __restrict__ basePe,
                      float* __restrict__ out) {
    int row = blockIdx.x * 4 + (threadIdx.x >> 6);
    int lane = threadIdx.x & 63;
    int b = row >> 12;
    float ai = a[row];
    float cmin = hdr[b*2 + 0], scale = hdr[b*2 + 1];
    float t = (ai - cmin) * scale;
    int ib = t < 0.f ? 0 : (t >= (float)NB ? NB : (int)t);
    int k    = binstart[(size_t)b*(NB+2) + ib];
    int kend = binstart[(size_t)b*(NB+2) + ib + 1];
    float alpha = expf(cmin - ai);
    float Z = fmaf(alpha, (float)(LL - k), SEb[(size_t)b*(NB+2) + ib]);
    size_t db = (size_t)lane * 4;
    size_t totoff = ((size_t)b * (NC+1) + NC) * DD + db;
    float4 ptot  = *(const float4*)(baseP  + totoff);
    float4 pk, pek;
    if (k < LL) {
        int q = k >> 5;
        size_t po = ((size_t)b * LL + k) * DD + db;
        size_t bo = ((size_t)b * (NC+1) + q) * DD + db;
        float4 pl = *(const float4*)(Pl    + po);
        float4 bp = *(const float4*)(baseP + bo);
        float4 pe = *(const float4*)(Pel    + po);
        float4 be = *(const float4*)(basePe + bo);
        pk.x = pl.x + bp.x; pk.y = pl.y + bp.y; pk.z = pl.z + bp.z; pk.w = pl.w + bp.w;
        pek.x = pe.x + be.x; pek.y = pe.y + be.y; pek.z = pe.z + be.z; pek.w = pe.w + be.w;
    } else {
        pk = ptot;
        pek = *(const float4*)(basePe + totoff);
    }
    float4 num;
    num.x = fmaf(alpha, ptot.x - pk.x, pek.x);
    num.y = fmaf(alpha, ptot.y - pk.y, pek.y);
    num.z = fmaf(alpha, ptot.z - pk.z, pek.z);
    num.w = fmaf(alpha, ptot.w - pk.w, pek.w);
    for (int r = k; r < kend; ++r) {
        float cr = c_sorted[(size_t)b*LL + r];
        if (cr < ai) {
            float w = e_sorted[(size_t)b*LL + r] - alpha;
            int j = perm[(size_t)b*LL + r];
            float4 v = *(const float4*)(V + ((size_t)b*LL + j) * DD + db);
            num.x = fmaf(w, v.x, num.x);
            num.y = fmaf(w, v.y, num.y);
            num.z = fmaf(w, v.z, num.z);
            num.w = fmaf(w, v.w, num.w);
            Z += w;
        }
    }
    float invZ = 1.f / Z;
    float4 o;
    o.x = num.x * invZ; o.y = num.y * invZ; o.z = num.z * invZ; o.w = num.w * invZ;
    *(float4*)(out + (size_t)row * DD + db) = o;
}

extern "C" void kernel_launch(void* const* d_in, const int* in_sizes, int n_in,
                              void* d_out, int out_size, void* d_ws, size_t ws_size,
                              hipStream_t stream) {
    const float* x  = (const float*)d_in[0];
    const float* Wq = (const float*)d_in[1];
    const float* Wk = (const float*)d_in[2];
    const float* Wv = (const float*)d_in[3];
    const float* wm = (const float*)d_in[4];
    const float* bm = (const float*)d_in[5];
    float* out = (float*)d_out;
    float* ws = (float*)d_ws;

    size_t off = 0;
    auto alloc = [&](size_t n) {      // n in floats
        float* p = ws + off;
        off += (n + 255) & ~(size_t)255;
        return p;
    };
    float* u        = alloc(2*DD);
    float* a        = alloc(NROWS);
    float* c        = alloc(NROWS);
    float* c_sorted = alloc(NROWS);
    float* e_sorted = alloc(NROWS);
    float* SEb      = alloc((size_t)BB*(NB+2));
    int*   perm     = (int*)alloc(NROWS);
    int*   binstart = (int*)alloc((size_t)BB*(NB+2));
    float* hdr      = alloc(2*BB);
    float* V        = alloc((size_t)NROWS*DD);
    float* Pl       = alloc((size_t)NROWS*DD);
    float* Pel      = alloc((size_t)NROWS*DD);
    float* Tp       = alloc((size_t)BB*NC*DD);
    float* Te       = alloc((size_t)BB*NC*DD);
    float* baseP    = alloc((size_t)BB*(NC+1)*DD);
    float* basePe   = alloc((size_t)BB*(NC+1)*DD);
    __bf16* Wh      = (__bf16*)alloc((size_t)DD*DD/2);
    __bf16* Wl      = (__bf16*)alloc((size_t)DD*DD/2);

    hipLaunchKernelGGL(k_prep, dim3(16), dim3(256), 0, stream, Wq, Wk, Wv, wm, u, Wh, Wl);
    hipLaunchKernelGGL(k_gemm_mfma, dim3(NROWS/32), dim3(256), 0, stream,
                       x, Wh, Wl, u, bm, V, a, c);
    hipLaunchKernelGGL(k_sortish, dim3(BB), dim3(1024), 0, stream,
                       c, binstart, SEb, perm, c_sorted, e_sorted, hdr);
    hipLaunchKernelGGL(k_scan, dim3(NC, BB), dim3(DD), 0, stream, V, perm, e_sorted, Pl, Pel, Tp, Te);
    hipLaunchKernelGGL(k_base, dim3(NC+1, BB), dim3(DD), 0, stream, Tp, Te, baseP, basePe);
    hipLaunchKernelGGL(k_out, dim3(NROWS/4), dim3(256), 0, stream,
                       a, hdr, binstart, SEb, c_sorted, e_sorted, perm, V,
                       Pl, Pel, baseP, basePe, out);
}